// Round 2
// baseline (2770.695 us; speedup 1.0000x reference)
//
#include <hip/hip_runtime.h>
#include <hip/hip_bf16.h>
#include <stdint.h>

typedef __attribute__((ext_vector_type(8))) short short8;
typedef __attribute__((ext_vector_type(4))) float f32x4;

#define LN_EPS 1e-5f

__device__ __forceinline__ ushort f2bf(float f) {
  union { float f; uint32_t u; } v; v.f = f;
  uint32_t u = v.u;
  return (ushort)((u + 0x7FFFu + ((u >> 16) & 1u)) >> 16);
}
__device__ __forceinline__ float bf2f(ushort b) {
  union { uint32_t u; float f; } v; v.u = ((uint32_t)b) << 16;
  return v.f;
}

// ---------------- small kernels ----------------

__global__ void conv_bf16_kernel(const float* __restrict__ src, ushort* __restrict__ dst, int n) {
  int i = blockIdx.x * 256 + threadIdx.x;
  if (i < n) dst[i] = f2bf(src[i]);
}

__global__ void zero_kernel(float* __restrict__ p, int n) {
  int i = blockIdx.x * 256 + threadIdx.x;
  if (i < n) p[i] = 0.f;
}

__global__ void embed_kernel(const float* __restrict__ x, const float* __restrict__ Win,
                             const float* __restrict__ b_in, float* __restrict__ h, int N) {
  int i = blockIdx.x * 256 + threadIdx.x;
  if (i >= N * 128) return;
  int n = i >> 7, d = i & 127;
  float v = Win[d*3+0]*x[n*3+0] + Win[d*3+1]*x[n*3+1] + Win[d*3+2]*x[n*3+2] + b_in[d];
  h[i] = fmaxf(v, 0.f);
}

__global__ void deg_kernel(const int* __restrict__ ei, float* __restrict__ degf, int E) {
  int e = blockIdx.x * 256 + threadIdx.x;
  if (e < E) atomicAdd(&degf[ei[E + e]], 1.0f);
}

__global__ void z_kernel(const float* __restrict__ h, const float* __restrict__ wd,
                         const float* __restrict__ bd, const float* __restrict__ degf,
                         float* __restrict__ u, int N) {
  int row = blockIdx.x * 4 + (threadIdx.x >> 6);
  int lane = threadIdx.x & 63;
  if (row >= N) return;
  const float* hr = h + (size_t)row * 128;
  float s = hr[lane] * wd[lane] + hr[64 + lane] * wd[64 + lane];
  #pragma unroll
  for (int o = 32; o >= 1; o >>= 1) s += __shfl_xor(s, o, 64);
  if (lane == 0) {
    float z = fmaxf(s + bd[0], 0.f);
    u[row] = z * rsqrtf(degf[row] + 1.0f);   // deg includes self-loop (+1), always >=1
  }
}

__global__ void scatter_kernel(const int* __restrict__ ei, const float* __restrict__ u,
                               float* __restrict__ t, int E) {
  int e = blockIdx.x * 256 + threadIdx.x;
  if (e < E) atomicAdd(&t[ei[E + e]], u[ei[e]]);
}

__global__ void out_kernel(const float* __restrict__ degf, const float* __restrict__ u,
                           const float* __restrict__ t, const float* __restrict__ wg,
                           const float* __restrict__ bg, const float* __restrict__ wf,
                           const float* __restrict__ bfp, float* __restrict__ out, int N) {
  int n = blockIdx.x * 256 + threadIdx.x;
  if (n >= N) return;
  float dis = rsqrtf(degf[n] + 1.0f);
  float tf = dis * (t[n] + u[n]);   // = dis*(sum_edges u[row] + self u[n])
  float acc = bfp[0];
  #pragma unroll
  for (int j = 0; j < 32; ++j) acc += wf[j] * fmaxf(tf * wg[j] + bg[j], 0.f);
  out[n] = acc;
}

// ---------------- fused transformer layer ----------------
// Block: 512 threads (8 waves), 256 rows. LDS: hA[256][128]bf16 (swz) + ubuf[256][64]bf16
// + wbuf 32KB = 128KB. All MFMA 16x16x32 bf16; A-frag row=lane&15,k=8*(lane>>4)+j;
// B-frag col=lane&15; C/D col=lane&15,row=4*(lane>>4)+reg.

#define MFMA16(a, b, c) __builtin_amdgcn_mfma_f32_16x16x32_bf16(a, b, c, 0, 0, 0)

__global__ __launch_bounds__(512, 2) void layer_kernel(
    float* __restrict__ h,
    const ushort* __restrict__ Wv, const ushort* __restrict__ Wo,
    const ushort* __restrict__ W1, const ushort* __restrict__ W2,
    const float* __restrict__ bv, const float* __restrict__ bo,
    const float* __restrict__ b1, const float* __restrict__ b2,
    const float* __restrict__ g1, const float* __restrict__ be1,
    const float* __restrict__ g2, const float* __restrict__ be2,
    int N)
{
  __shared__ ushort hA[256 * 128];    // row stride 256B, swz: byte ^= (row&7)<<4
  __shared__ ushort ubuf[256 * 64];   // row stride 128B, same swz
  __shared__ ushort wbuf[128 * 128];  // Wv/Wo [128][128]; or W1c[64][128] + W2c[128][64]@+16KB

  const int tid = threadIdx.x;
  const int lane = tid & 63;
  const int wave = tid >> 6;
  const int l15 = lane & 15;
  const int lg = lane >> 4;
  const int rowbase = blockIdx.x * 256;
  const int wrow = wave * 32;
  const int ssw = (l15 & 7) << 4;

  // ---- stage h (fp32 global -> bf16 LDS, swizzled) ----
  for (int c = tid; c < 256 * 16; c += 512) {
    int row = c >> 4, k8 = c & 15;
    int g = rowbase + row;
    float4 f0 = make_float4(0.f, 0.f, 0.f, 0.f), f1 = f0;
    if (g < N) {
      const float4* p = (const float4*)(h + (size_t)g * 128 + k8 * 8);
      f0 = p[0]; f1 = p[1];
    }
    short8 v;
    v[0]=(short)f2bf(f0.x); v[1]=(short)f2bf(f0.y); v[2]=(short)f2bf(f0.z); v[3]=(short)f2bf(f0.w);
    v[4]=(short)f2bf(f1.x); v[5]=(short)f2bf(f1.y); v[6]=(short)f2bf(f1.z); v[7]=(short)f2bf(f1.w);
    *(short8*)((char*)hA + ((row << 8) + ((k8 << 4) ^ ((row & 7) << 4)))) = v;
  }
  // ---- stage Wv ----
  for (int c = tid; c < 2048; c += 512) {
    int row = c >> 4, k8 = c & 15;
    short8 v = *(const short8*)(Wv + row * 128 + k8 * 8);
    *(short8*)((char*)wbuf + ((row << 8) + ((k8 << 4) ^ ((row & 7) << 4)))) = v;
  }
  __syncthreads();

  // ---- GEMM1: t = h @ Wv^T ----
  f32x4 tC[2][8];
  #pragma unroll
  for (int rt = 0; rt < 2; ++rt)
    #pragma unroll
    for (int nt = 0; nt < 8; ++nt) tC[rt][nt] = (f32x4){0.f, 0.f, 0.f, 0.f};
  #pragma unroll
  for (int ks = 0; ks < 4; ++ks) {
    int asw = (ks * 64 + lg * 16) ^ ssw;
    short8 a0 = *(const short8*)((char*)hA + (((wrow + l15) << 8) + asw));
    short8 a1 = *(const short8*)((char*)hA + (((wrow + 16 + l15) << 8) + asw));
    #pragma unroll
    for (int nt = 0; nt < 8; ++nt) {
      short8 b = *(const short8*)((char*)wbuf + (((nt * 16 + l15) << 8) + asw));
      tC[0][nt] = MFMA16(a0, b, tC[0][nt]);
      tC[1][nt] = MFMA16(a1, b, tC[1][nt]);
    }
  }
  // t + bv -> hA (bf16). Each wave writes only its own 32 rows.
  #pragma unroll
  for (int nt = 0; nt < 8; ++nt) {
    int col = nt * 16 + l15;
    float bvv = bv[col];
    #pragma unroll
    for (int rt = 0; rt < 2; ++rt)
      #pragma unroll
      for (int j = 0; j < 4; ++j) {
        int lr = wrow + rt * 16 + lg * 4 + j;
        *(ushort*)((char*)hA + ((lr << 8) + ((col * 2) ^ ((lr & 7) << 4)))) =
            f2bf(tC[rt][nt][j] + bvv);
      }
  }
  __syncthreads();
  // ---- stage Wo ----
  for (int c = tid; c < 2048; c += 512) {
    int row = c >> 4, k8 = c & 15;
    short8 v = *(const short8*)(Wo + row * 128 + k8 * 8);
    *(short8*)((char*)wbuf + ((row << 8) + ((k8 << 4) ^ ((row & 7) << 4)))) = v;
  }
  __syncthreads();

  // ---- GEMM2: attn = t @ Wo^T ----
  #pragma unroll
  for (int rt = 0; rt < 2; ++rt)
    #pragma unroll
    for (int nt = 0; nt < 8; ++nt) tC[rt][nt] = (f32x4){0.f, 0.f, 0.f, 0.f};
  #pragma unroll
  for (int ks = 0; ks < 4; ++ks) {
    int asw = (ks * 64 + lg * 16) ^ ssw;
    short8 a0 = *(const short8*)((char*)hA + (((wrow + l15) << 8) + asw));
    short8 a1 = *(const short8*)((char*)hA + (((wrow + 16 + l15) << 8) + asw));
    #pragma unroll
    for (int nt = 0; nt < 8; ++nt) {
      short8 b = *(const short8*)((char*)wbuf + (((nt * 16 + l15) << 8) + asw));
      tC[0][nt] = MFMA16(a0, b, tC[0][nt]);
      tC[1][nt] = MFMA16(a1, b, tC[1][nt]);
    }
  }

  // ---- residual (fp32 re-read of h) + bo, LayerNorm1 -> h1 (bf16) into hA ----
  float sum[2][4] = {{0.f,0.f,0.f,0.f},{0.f,0.f,0.f,0.f}};
  float sq[2][4]  = {{0.f,0.f,0.f,0.f},{0.f,0.f,0.f,0.f}};
  #pragma unroll
  for (int nt = 0; nt < 8; ++nt) {
    int col = nt * 16 + l15;
    float bov = bo[col];
    #pragma unroll
    for (int rt = 0; rt < 2; ++rt)
      #pragma unroll
      for (int j = 0; j < 4; ++j) {
        int g = rowbase + wrow + rt * 16 + lg * 4 + j;
        float hv = (g < N) ? h[(size_t)g * 128 + col] : 0.f;
        float v = tC[rt][nt][j] + bov + hv;
        tC[rt][nt][j] = v;
        sum[rt][j] += v; sq[rt][j] += v * v;
      }
  }
  #pragma unroll
  for (int o = 1; o < 16; o <<= 1)
    #pragma unroll
    for (int rt = 0; rt < 2; ++rt)
      #pragma unroll
      for (int j = 0; j < 4; ++j) {
        sum[rt][j] += __shfl_xor(sum[rt][j], o, 64);
        sq[rt][j]  += __shfl_xor(sq[rt][j],  o, 64);
      }
  float mean[2][4], rstd[2][4];
  #pragma unroll
  for (int rt = 0; rt < 2; ++rt)
    #pragma unroll
    for (int j = 0; j < 4; ++j) {
      mean[rt][j] = sum[rt][j] * (1.f / 128.f);
      float var = sq[rt][j] * (1.f / 128.f) - mean[rt][j] * mean[rt][j];
      rstd[rt][j] = rsqrtf(var + LN_EPS);
    }
  #pragma unroll
  for (int nt = 0; nt < 8; ++nt) {
    int col = nt * 16 + l15;
    float g1v = g1[col], b1v = be1[col];
    #pragma unroll
    for (int rt = 0; rt < 2; ++rt)
      #pragma unroll
      for (int j = 0; j < 4; ++j) {
        int lr = wrow + rt * 16 + lg * 4 + j;
        float hh = (tC[rt][nt][j] - mean[rt][j]) * rstd[rt][j] * g1v + b1v;
        *(ushort*)((char*)hA + ((lr << 8) + ((col * 2) ^ ((lr & 7) << 4)))) = f2bf(hh);
      }
  }

  // ---- FF: acc = relu(h1@W1c^T + b1c) @ W2c^T, chunked over F (64 at a time) ----
  f32x4 acc[2][8];
  #pragma unroll
  for (int rt = 0; rt < 2; ++rt)
    #pragma unroll
    for (int nt = 0; nt < 8; ++nt) acc[rt][nt] = (f32x4){0.f, 0.f, 0.f, 0.f};

  for (int ch = 0; ch < 32; ++ch) {
    __syncthreads();   // previous chunk's wbuf readers done
    const ushort* W1c = W1 + ch * 64 * 128;
    const ushort* W2c = W2 + ch * 64;
    for (int c = tid; c < 2048; c += 512) {
      if (c < 1024) {
        int row = c >> 4, k8 = c & 15;
        short8 v = *(const short8*)(W1c + row * 128 + k8 * 8);
        *(short8*)((char*)wbuf + ((row << 8) + ((k8 << 4) ^ ((row & 7) << 4)))) = v;
      } else {
        int cc = c - 1024;
        int row = cc >> 3, k8 = cc & 7;
        short8 v = *(const short8*)(W2c + (size_t)row * 2048 + k8 * 8);
        *(short8*)((char*)wbuf + 16384 + ((row << 7) + ((k8 << 4) ^ ((row & 7) << 4)))) = v;
      }
    }
    __syncthreads();

    f32x4 uC[2][4];
    #pragma unroll
    for (int rt = 0; rt < 2; ++rt)
      #pragma unroll
      for (int nt = 0; nt < 4; ++nt) uC[rt][nt] = (f32x4){0.f, 0.f, 0.f, 0.f};
    #pragma unroll
    for (int ks = 0; ks < 4; ++ks) {
      int asw = (ks * 64 + lg * 16) ^ ssw;
      short8 a0 = *(const short8*)((char*)hA + (((wrow + l15) << 8) + asw));
      short8 a1 = *(const short8*)((char*)hA + (((wrow + 16 + l15) << 8) + asw));
      #pragma unroll
      for (int nt = 0; nt < 4; ++nt) {
        short8 b = *(const short8*)((char*)wbuf + (((nt * 16 + l15) << 8) + asw));
        uC[0][nt] = MFMA16(a0, b, uC[0][nt]);
        uC[1][nt] = MFMA16(a1, b, uC[1][nt]);
      }
    }
    // bias + relu -> ubuf (bf16)
    #pragma unroll
    for (int nt = 0; nt < 4; ++nt) {
      int f = nt * 16 + l15;
      float b1v = b1[ch * 64 + f];
      #pragma unroll
      for (int rt = 0; rt < 2; ++rt)
        #pragma unroll
        for (int j = 0; j < 4; ++j) {
          int lr = wrow + rt * 16 + lg * 4 + j;
          float v = fmaxf(uC[rt][nt][j] + b1v, 0.f);
          *(ushort*)((char*)ubuf + ((lr << 7) + ((f * 2) ^ ((lr & 7) << 4)))) = f2bf(v);
        }
    }
    // acc += u @ W2c^T
    #pragma unroll
    for (int ks = 0; ks < 2; ++ks) {
      int asw = (ks * 64 + lg * 16) ^ ssw;
      short8 a0 = *(const short8*)((char*)ubuf + (((wrow + l15) << 7) + asw));
      short8 a1 = *(const short8*)((char*)ubuf + (((wrow + 16 + l15) << 7) + asw));
      #pragma unroll
      for (int nt = 0; nt < 8; ++nt) {
        short8 b = *(const short8*)((char*)wbuf + 16384 + (((nt * 16 + l15) << 7) + asw));
        acc[0][nt] = MFMA16(a0, b, acc[0][nt]);
        acc[1][nt] = MFMA16(a1, b, acc[1][nt]);
      }
    }
  }

  // ---- residual2 (h1 from hA, bf16) + b2, LayerNorm2 -> h (fp32 global) ----
  #pragma unroll
  for (int rt = 0; rt < 2; ++rt)
    #pragma unroll
    for (int j = 0; j < 4; ++j) { sum[rt][j] = 0.f; sq[rt][j] = 0.f; }
  #pragma unroll
  for (int nt = 0; nt < 8; ++nt) {
    int col = nt * 16 + l15;
    float b2v = b2[col];
    #pragma unroll
    for (int rt = 0; rt < 2; ++rt)
      #pragma unroll
      for (int j = 0; j < 4; ++j) {
        int lr = wrow + rt * 16 + lg * 4 + j;
        float h1v = bf2f(*(const ushort*)((char*)hA + ((lr << 8) + ((col * 2) ^ ((lr & 7) << 4)))));
        float v = acc[rt][nt][j] + b2v + h1v;
        acc[rt][nt][j] = v;
        sum[rt][j] += v; sq[rt][j] += v * v;
      }
  }
  #pragma unroll
  for (int o = 1; o < 16; o <<= 1)
    #pragma unroll
    for (int rt = 0; rt < 2; ++rt)
      #pragma unroll
      for (int j = 0; j < 4; ++j) {
        sum[rt][j] += __shfl_xor(sum[rt][j], o, 64);
        sq[rt][j]  += __shfl_xor(sq[rt][j],  o, 64);
      }
  #pragma unroll
  for (int rt = 0; rt < 2; ++rt)
    #pragma unroll
    for (int j = 0; j < 4; ++j) {
      mean[rt][j] = sum[rt][j] * (1.f / 128.f);
      float var = sq[rt][j] * (1.f / 128.f) - mean[rt][j] * mean[rt][j];
      rstd[rt][j] = rsqrtf(var + LN_EPS);
    }
  #pragma unroll
  for (int nt = 0; nt < 8; ++nt) {
    int col = nt * 16 + l15;
    float g2v = g2[col], b2lv = be2[col];
    #pragma unroll
    for (int rt = 0; rt < 2; ++rt)
      #pragma unroll
      for (int j = 0; j < 4; ++j) {
        int g = rowbase + wrow + rt * 16 + lg * 4 + j;
        if (g < N)
          h[(size_t)g * 128 + col] = (acc[rt][nt][j] - mean[rt][j]) * rstd[rt][j] * g2v + b2lv;
      }
  }
}

// ---------------- launcher ----------------

extern "C" void kernel_launch(void* const* d_in, const int* in_sizes, int n_in,
                              void* d_out, int out_size, void* d_ws, size_t ws_size,
                              hipStream_t stream) {
  const float* x   = (const float*)d_in[0];
  const int*   ei  = (const int*)d_in[1];
  const float* Win = (const float*)d_in[2];
  const float* b_in= (const float*)d_in[3];
  const float* Wv  = (const float*)d_in[4];
  const float* bv  = (const float*)d_in[5];
  const float* Wo  = (const float*)d_in[6];
  const float* bo  = (const float*)d_in[7];
  const float* W1  = (const float*)d_in[8];
  const float* b1  = (const float*)d_in[9];
  const float* W2  = (const float*)d_in[10];
  const float* b2  = (const float*)d_in[11];
  const float* ln1g= (const float*)d_in[12];
  const float* ln1b= (const float*)d_in[13];
  const float* ln2g= (const float*)d_in[14];
  const float* ln2b= (const float*)d_in[15];
  const float* Wd  = (const float*)d_in[16];
  const float* bd  = (const float*)d_in[17];
  const float* Wg  = (const float*)d_in[18];
  const float* bg  = (const float*)d_in[19];
  const float* Wf  = (const float*)d_in[20];
  const float* bfp = (const float*)d_in[21];

  const int N = in_sizes[0] / 3;
  const int E = in_sizes[1] / 2;

  char* ws = (char*)d_ws;
  float* h = (float*)ws;                     size_t off = (size_t)N * 128 * 4;
  ushort* Wvb = (ushort*)(ws + off);         off += (size_t)3 * 16384 * 2;
  ushort* Wob = (ushort*)(ws + off);         off += (size_t)3 * 16384 * 2;
  ushort* W1b = (ushort*)(ws + off);         off += (size_t)3 * 262144 * 2;
  ushort* W2b = (ushort*)(ws + off);         off += (size_t)3 * 262144 * 2;
  float* degf = (float*)(ws + off);          off += (size_t)N * 4;
  float* tarr = (float*)(ws + off);          off += (size_t)N * 4;
  float* uarr = (float*)(ws + off);          off += (size_t)N * 4;

  conv_bf16_kernel<<<(3 * 16384 + 255) / 256, 256, 0, stream>>>(Wv, Wvb, 3 * 16384);
  conv_bf16_kernel<<<(3 * 16384 + 255) / 256, 256, 0, stream>>>(Wo, Wob, 3 * 16384);
  conv_bf16_kernel<<<(3 * 262144 + 255) / 256, 256, 0, stream>>>(W1, W1b, 3 * 262144);
  conv_bf16_kernel<<<(3 * 262144 + 255) / 256, 256, 0, stream>>>(W2, W2b, 3 * 262144);
  zero_kernel<<<(2 * N + 255) / 256, 256, 0, stream>>>(degf, 2 * N);  // degf + tarr (adjacent)

  embed_kernel<<<((size_t)N * 128 + 255) / 256, 256, 0, stream>>>(x, Win, b_in, h, N);
  deg_kernel<<<(E + 255) / 256, 256, 0, stream>>>(ei, degf, E);

  const int grid = (N + 255) / 256;
  for (int l = 0; l < 3; ++l) {
    layer_kernel<<<grid, 512, 0, stream>>>(
        h,
        Wvb + (size_t)l * 16384, Wob + (size_t)l * 16384,
        W1b + (size_t)l * 262144, W2b + (size_t)l * 262144,
        bv + l * 128, bo + l * 128, b1 + l * 2048, b2 + l * 128,
        ln1g + l * 128, ln1b + l * 128, ln2g + l * 128, ln2b + l * 128,
        N);
  }

  z_kernel<<<(N + 3) / 4, 256, 0, stream>>>(h, Wd, bd, degf, uarr, N);
  scatter_kernel<<<(E + 255) / 256, 256, 0, stream>>>(ei, uarr, tarr, E);
  out_kernel<<<(N + 255) / 256, 256, 0, stream>>>(degf, uarr, tarr, Wg, bg, Wf, bfp,
                                                  (float*)d_out, N);
}

// Round 3
// 2372.868 us; speedup vs baseline: 1.1677x; 1.1677x over previous
//
#include <hip/hip_runtime.h>
#include <hip/hip_bf16.h>
#include <stdint.h>

typedef __attribute__((ext_vector_type(8))) short short8;
typedef __attribute__((ext_vector_type(4))) float f32x4;

#define LN_EPS 1e-5f

__device__ __forceinline__ ushort f2bf(float f) {
  union { float f; uint32_t u; } v; v.f = f;
  uint32_t u = v.u;
  return (ushort)((u + 0x7FFFu + ((u >> 16) & 1u)) >> 16);
}
__device__ __forceinline__ float bf2f(ushort b) {
  union { uint32_t u; float f; } v; v.u = ((uint32_t)b) << 16;
  return v.f;
}

// ---------------- small kernels ----------------

__global__ void conv_bf16_kernel(const float* __restrict__ src, ushort* __restrict__ dst, int n) {
  int i = blockIdx.x * 256 + threadIdx.x;
  if (i < n) dst[i] = f2bf(src[i]);
}

__global__ void zero_kernel(float* __restrict__ p, int n) {
  int i = blockIdx.x * 256 + threadIdx.x;
  if (i < n) p[i] = 0.f;
}

__global__ void embed_kernel(const float* __restrict__ x, const float* __restrict__ Win,
                             const float* __restrict__ b_in, float* __restrict__ h, int N) {
  int i = blockIdx.x * 256 + threadIdx.x;
  if (i >= N * 128) return;
  int n = i >> 7, d = i & 127;
  float v = Win[d*3+0]*x[n*3+0] + Win[d*3+1]*x[n*3+1] + Win[d*3+2]*x[n*3+2] + b_in[d];
  h[i] = fmaxf(v, 0.f);
}

// 4 edges per thread, int4 loads
__global__ void deg_kernel(const int* __restrict__ ei, float* __restrict__ degf, int E) {
  int i = blockIdx.x * 256 + threadIdx.x;
  int e0 = i * 4;
  if (e0 + 3 < E) {
    int4 c = *(const int4*)(ei + E + e0);
    atomicAdd(&degf[c.x], 1.0f); atomicAdd(&degf[c.y], 1.0f);
    atomicAdd(&degf[c.z], 1.0f); atomicAdd(&degf[c.w], 1.0f);
  } else {
    for (int e = e0; e < E; ++e) atomicAdd(&degf[ei[E + e]], 1.0f);
  }
}

__global__ void z_kernel(const float* __restrict__ h, const float* __restrict__ wd,
                         const float* __restrict__ bd, const float* __restrict__ degf,
                         float* __restrict__ u, int N) {
  int row = blockIdx.x * 4 + (threadIdx.x >> 6);
  int lane = threadIdx.x & 63;
  if (row >= N) return;
  const float* hr = h + (size_t)row * 128;
  float s = hr[lane] * wd[lane] + hr[64 + lane] * wd[64 + lane];
  #pragma unroll
  for (int o = 32; o >= 1; o >>= 1) s += __shfl_xor(s, o, 64);
  if (lane == 0) {
    float z = fmaxf(s + bd[0], 0.f);
    u[row] = z * rsqrtf(degf[row] + 1.0f);   // deg includes self-loop (+1), always >=1
  }
}

__global__ void scatter_kernel(const int* __restrict__ ei, const float* __restrict__ u,
                               float* __restrict__ t, int E) {
  int i = blockIdx.x * 256 + threadIdx.x;
  int e0 = i * 4;
  if (e0 + 3 < E) {
    int4 r = *(const int4*)(ei + e0);
    int4 c = *(const int4*)(ei + E + e0);
    atomicAdd(&t[c.x], u[r.x]); atomicAdd(&t[c.y], u[r.y]);
    atomicAdd(&t[c.z], u[r.z]); atomicAdd(&t[c.w], u[r.w]);
  } else {
    for (int e = e0; e < E; ++e) atomicAdd(&t[ei[E + e]], u[ei[e]]);
  }
}

__global__ void out_kernel(const float* __restrict__ degf, const float* __restrict__ u,
                           const float* __restrict__ t, const float* __restrict__ wg,
                           const float* __restrict__ bg, const float* __restrict__ wf,
                           const float* __restrict__ bfp, float* __restrict__ out, int N) {
  int n = blockIdx.x * 256 + threadIdx.x;
  if (n >= N) return;
  float dis = rsqrtf(degf[n] + 1.0f);
  float tf = dis * (t[n] + u[n]);   // = dis*(sum_edges u[row] + self u[n])
  float acc = bfp[0];
  #pragma unroll
  for (int j = 0; j < 32; ++j) acc += wf[j] * fmaxf(tf * wg[j] + bg[j], 0.f);
  out[n] = acc;
}

// ---------------- fused transformer layer ----------------
// 128-row tile, 512 threads (8 waves, 16 rows/wave). LDS = hA 32KB + ubuf 16KB +
// wbuf 32KB = 80KB -> 2 blocks/CU (4 waves/SIMD) for cross-block latency hiding.
// All weight stages are reg-prefetched (T14): global->reg issued under previous
// MFMA phase, ds_write after the barrier. hA/ubuf rows are wave-private after the
// initial stage, so only wbuf cycling needs barriers.
// MFMA 16x16x32 bf16; A: row=lane&15,k=8*(lane>>4)+j; B: col=lane&15; C/D:
// col=lane&15,row=4*(lane>>4)+reg (m89-verified).

#define MFMA16(a, b, c) __builtin_amdgcn_mfma_f32_16x16x32_bf16(a, b, c, 0, 0, 0)

__global__ __launch_bounds__(512, 4) void layer_kernel(
    float* __restrict__ h,
    const ushort* __restrict__ Wv, const ushort* __restrict__ Wo,
    const ushort* __restrict__ W1, const ushort* __restrict__ W2,
    const float* __restrict__ bv, const float* __restrict__ bo,
    const float* __restrict__ b1, const float* __restrict__ b2,
    const float* __restrict__ g1, const float* __restrict__ be1,
    const float* __restrict__ g2, const float* __restrict__ be2,
    int N)
{
  __shared__ ushort hA[128 * 128];    // row stride 256B, swz: byte ^= (row&7)<<4
  __shared__ ushort ubuf[128 * 64];   // row stride 128B, same swz
  __shared__ ushort wbuf[128 * 128];  // attn: Wv/Wo [128][128]; FF: W1c[64][128] + W2c[128][64]@short 8192

  const int tid = threadIdx.x;
  const int lane = tid & 63;
  const int wave = tid >> 6;
  const int l15 = lane & 15;
  const int lg = lane >> 4;
  const int rowbase = blockIdx.x * 128;
  const int wrow = wave * 16;
  const int ssw = (l15 & 7) << 4;

  // ---- prefetch h tile (fp32) + Wv into regs ----
  float4 hf[8];
  short8 wr[4];
  #pragma unroll
  for (int i = 0; i < 4; ++i) {
    int u = tid + i * 512;          // unit = short8; row=u>>4, k8=u&15
    int g = rowbase + (u >> 4);
    float4 z4 = make_float4(0.f, 0.f, 0.f, 0.f);
    hf[2*i] = z4; hf[2*i+1] = z4;
    if (g < N) {
      const float4* p = (const float4*)(h + (size_t)g * 128 + (u & 15) * 8);
      hf[2*i] = p[0]; hf[2*i+1] = p[1];
    }
    wr[i] = *(const short8*)(Wv + u * 8);
  }
  // ---- write to LDS (swizzled) ----
  #pragma unroll
  for (int i = 0; i < 4; ++i) {
    int u = tid + i * 512;
    int row = u >> 4, k8 = u & 15;
    int off = (row << 8) + ((k8 << 4) ^ ((row & 7) << 4));
    short8 v;
    v[0]=(short)f2bf(hf[2*i].x); v[1]=(short)f2bf(hf[2*i].y);
    v[2]=(short)f2bf(hf[2*i].z); v[3]=(short)f2bf(hf[2*i].w);
    v[4]=(short)f2bf(hf[2*i+1].x); v[5]=(short)f2bf(hf[2*i+1].y);
    v[6]=(short)f2bf(hf[2*i+1].z); v[7]=(short)f2bf(hf[2*i+1].w);
    *(short8*)((char*)hA + off) = v;
    *(short8*)((char*)wbuf + off) = wr[i];
  }
  __syncthreads();

  // issue Wo prefetch (hidden under GEMM1)
  #pragma unroll
  for (int i = 0; i < 4; ++i) wr[i] = *(const short8*)(Wo + (tid + i * 512) * 8);

  // ---- GEMM1: t = h @ Wv^T ----
  f32x4 tC[8];
  #pragma unroll
  for (int nt = 0; nt < 8; ++nt) tC[nt] = (f32x4){0.f, 0.f, 0.f, 0.f};
  __builtin_amdgcn_s_setprio(1);
  #pragma unroll
  for (int ks = 0; ks < 4; ++ks) {
    int asw = (ks * 64 + lg * 16) ^ ssw;
    short8 a0 = *(const short8*)((char*)hA + (((wrow + l15) << 8) + asw));
    #pragma unroll
    for (int nt = 0; nt < 8; ++nt) {
      short8 b = *(const short8*)((char*)wbuf + (((nt * 16 + l15) << 8) + asw));
      tC[nt] = MFMA16(a0, b, tC[nt]);
    }
  }
  __builtin_amdgcn_s_setprio(0);
  // t + bv -> hA (own 16 rows; no barrier needed for hA)
  #pragma unroll
  for (int nt = 0; nt < 8; ++nt) {
    int col = nt * 16 + l15;
    float bvv = bv[col];
    #pragma unroll
    for (int j = 0; j < 4; ++j) {
      int lr = wrow + lg * 4 + j;
      *(ushort*)((char*)hA + ((lr << 8) + ((col * 2) ^ ((lr & 7) << 4)))) =
          f2bf(tC[nt][j] + bvv);
    }
  }
  __syncthreads();                    // all waves done reading wbuf (Wv)
  #pragma unroll
  for (int i = 0; i < 4; ++i) {
    int u = tid + i * 512;
    int row = u >> 4, k8 = u & 15;
    *(short8*)((char*)wbuf + ((row << 8) + ((k8 << 4) ^ ((row & 7) << 4)))) = wr[i];
  }
  __syncthreads();                    // Wo ready

  // issue residual-h prefetch + FF chunk0 prefetch (hidden under GEMM2)
  float hres[8][4];
  #pragma unroll
  for (int j = 0; j < 4; ++j) {
    int g = rowbase + wrow + lg * 4 + j;
    #pragma unroll
    for (int nt = 0; nt < 8; ++nt)
      hres[nt][j] = (g < N) ? h[(size_t)g * 128 + nt * 16 + l15] : 0.f;
  }
  #pragma unroll
  for (int i = 0; i < 4; ++i) {
    int c = tid + i * 512;
    wr[i] = (c < 1024) ? *(const short8*)(W1 + c * 8)
                       : *(const short8*)(W2 + (size_t)((c - 1024) >> 3) * 2048 + ((c - 1024) & 7) * 8);
  }

  // ---- GEMM2: attn = t @ Wo^T ----
  #pragma unroll
  for (int nt = 0; nt < 8; ++nt) tC[nt] = (f32x4){0.f, 0.f, 0.f, 0.f};
  __builtin_amdgcn_s_setprio(1);
  #pragma unroll
  for (int ks = 0; ks < 4; ++ks) {
    int asw = (ks * 64 + lg * 16) ^ ssw;
    short8 a0 = *(const short8*)((char*)hA + (((wrow + l15) << 8) + asw));
    #pragma unroll
    for (int nt = 0; nt < 8; ++nt) {
      short8 b = *(const short8*)((char*)wbuf + (((nt * 16 + l15) << 8) + asw));
      tC[nt] = MFMA16(a0, b, tC[nt]);
    }
  }
  __builtin_amdgcn_s_setprio(0);

  // ---- residual1 + bo, LayerNorm1 -> h1 (bf16) into hA (own rows) ----
  float sum[4] = {0.f,0.f,0.f,0.f};
  float sq[4]  = {0.f,0.f,0.f,0.f};
  #pragma unroll
  for (int nt = 0; nt < 8; ++nt) {
    float bov = bo[nt * 16 + l15];
    #pragma unroll
    for (int j = 0; j < 4; ++j) {
      float v = tC[nt][j] + bov + hres[nt][j];
      tC[nt][j] = v;
      sum[j] += v; sq[j] += v * v;
    }
  }
  #pragma unroll
  for (int o = 1; o < 16; o <<= 1)
    #pragma unroll
    for (int j = 0; j < 4; ++j) {
      sum[j] += __shfl_xor(sum[j], o, 64);
      sq[j]  += __shfl_xor(sq[j],  o, 64);
    }
  float mean[4], rstd[4];
  #pragma unroll
  for (int j = 0; j < 4; ++j) {
    mean[j] = sum[j] * (1.f / 128.f);
    float var = sq[j] * (1.f / 128.f) - mean[j] * mean[j];
    rstd[j] = rsqrtf(var + LN_EPS);
  }
  #pragma unroll
  for (int nt = 0; nt < 8; ++nt) {
    int col = nt * 16 + l15;
    float g1v = g1[col], b1v = be1[col];
    #pragma unroll
    for (int j = 0; j < 4; ++j) {
      int lr = wrow + lg * 4 + j;
      float hh = (tC[nt][j] - mean[j]) * rstd[j] * g1v + b1v;
      *(ushort*)((char*)hA + ((lr << 8) + ((col * 2) ^ ((lr & 7) << 4)))) = f2bf(hh);
    }
  }

  __syncthreads();                    // all waves done reading wbuf (Wo)
  // write FF chunk0 weights, issue chunk1 prefetch
  #pragma unroll
  for (int i = 0; i < 4; ++i) {
    int c = tid + i * 512;
    if (c < 1024) {
      int row = c >> 4, k8 = c & 15;
      *(short8*)((char*)wbuf + ((row << 8) + ((k8 << 4) ^ ((row & 7) << 4)))) = wr[i];
    } else {
      int cc = c - 1024;
      int row = cc >> 3, k8 = cc & 7;
      *(short8*)((char*)wbuf + 16384 + ((row << 7) + ((k8 << 4) ^ ((row & 7) << 4)))) = wr[i];
    }
  }
  {
    const ushort* W1c = W1 + 1 * 64 * 128;
    const ushort* W2c = W2 + 1 * 64;
    #pragma unroll
    for (int i = 0; i < 4; ++i) {
      int c = tid + i * 512;
      wr[i] = (c < 1024) ? *(const short8*)(W1c + c * 8)
                         : *(const short8*)(W2c + (size_t)((c - 1024) >> 3) * 2048 + ((c - 1024) & 7) * 8);
    }
  }
  __syncthreads();                    // chunk0 ready

  // ---- FF: acc = relu(h1@W1c^T + b1c) @ W2c^T, 32 chunks of 64 ----
  f32x4 acc[8];
  #pragma unroll
  for (int nt = 0; nt < 8; ++nt) acc[nt] = (f32x4){0.f, 0.f, 0.f, 0.f};

  for (int ch = 0; ch < 32; ++ch) {
    f32x4 uC[4];
    #pragma unroll
    for (int nt = 0; nt < 4; ++nt) uC[nt] = (f32x4){0.f, 0.f, 0.f, 0.f};
    __builtin_amdgcn_s_setprio(1);
    #pragma unroll
    for (int ks = 0; ks < 4; ++ks) {
      int asw = (ks * 64 + lg * 16) ^ ssw;
      short8 a0 = *(const short8*)((char*)hA + (((wrow + l15) << 8) + asw));
      #pragma unroll
      for (int nt = 0; nt < 4; ++nt) {
        short8 b = *(const short8*)((char*)wbuf + (((nt * 16 + l15) << 8) + asw));
        uC[nt] = MFMA16(a0, b, uC[nt]);
      }
    }
    __builtin_amdgcn_s_setprio(0);
    // bias + relu -> ubuf (own rows)
    #pragma unroll
    for (int nt = 0; nt < 4; ++nt) {
      int f = nt * 16 + l15;
      float b1v = b1[ch * 64 + f];
      #pragma unroll
      for (int j = 0; j < 4; ++j) {
        int lr = wrow + lg * 4 + j;
        float v = fmaxf(uC[nt][j] + b1v, 0.f);
        *(ushort*)((char*)ubuf + ((lr << 7) + ((f * 2) ^ ((lr & 7) << 4)))) = f2bf(v);
      }
    }
    // acc += u @ W2c^T
    __builtin_amdgcn_s_setprio(1);
    #pragma unroll
    for (int ks = 0; ks < 2; ++ks) {
      int asw = (ks * 64 + lg * 16) ^ ssw;
      short8 a0 = *(const short8*)((char*)ubuf + (((wrow + l15) << 7) + asw));
      #pragma unroll
      for (int nt = 0; nt < 8; ++nt) {
        short8 b = *(const short8*)((char*)wbuf + 16384 + (((nt * 16 + l15) << 7) + asw));
        acc[nt] = MFMA16(a0, b, acc[nt]);
      }
    }
    __builtin_amdgcn_s_setprio(0);

    if (ch < 31) {
      __syncthreads();                // all waves done reading wbuf (chunk ch)
      #pragma unroll
      for (int i = 0; i < 4; ++i) {
        int c = tid + i * 512;
        if (c < 1024) {
          int row = c >> 4, k8 = c & 15;
          *(short8*)((char*)wbuf + ((row << 8) + ((k8 << 4) ^ ((row & 7) << 4)))) = wr[i];
        } else {
          int cc = c - 1024;
          int row = cc >> 3, k8 = cc & 7;
          *(short8*)((char*)wbuf + 16384 + ((row << 7) + ((k8 << 4) ^ ((row & 7) << 4)))) = wr[i];
        }
      }
      if (ch < 30) {
        const ushort* W1c = W1 + (size_t)(ch + 2) * 64 * 128;
        const ushort* W2c = W2 + (ch + 2) * 64;
        #pragma unroll
        for (int i = 0; i < 4; ++i) {
          int c = tid + i * 512;
          wr[i] = (c < 1024) ? *(const short8*)(W1c + c * 8)
                             : *(const short8*)(W2c + (size_t)((c - 1024) >> 3) * 2048 + ((c - 1024) & 7) * 8);
        }
      }
      __syncthreads();                // chunk ch+1 ready
    }
  }

  // ---- residual2 (h1 from hA) + b2, LayerNorm2 -> h (fp32 global) ----
  #pragma unroll
  for (int j = 0; j < 4; ++j) { sum[j] = 0.f; sq[j] = 0.f; }
  #pragma unroll
  for (int nt = 0; nt < 8; ++nt) {
    int col = nt * 16 + l15;
    float b2v = b2[col];
    #pragma unroll
    for (int j = 0; j < 4; ++j) {
      int lr = wrow + lg * 4 + j;
      float h1v = bf2f(*(const ushort*)((char*)hA + ((lr << 8) + ((col * 2) ^ ((lr & 7) << 4)))));
      float v = acc[nt][j] + b2v + h1v;
      acc[nt][j] = v;
      sum[j] += v; sq[j] += v * v;
    }
  }
  #pragma unroll
  for (int o = 1; o < 16; o <<= 1)
    #pragma unroll
    for (int j = 0; j < 4; ++j) {
      sum[j] += __shfl_xor(sum[j], o, 64);
      sq[j]  += __shfl_xor(sq[j],  o, 64);
    }
  #pragma unroll
  for (int j = 0; j < 4; ++j) {
    mean[j] = sum[j] * (1.f / 128.f);
    float var = sq[j] * (1.f / 128.f) - mean[j] * mean[j];
    rstd[j] = rsqrtf(var + LN_EPS);
  }
  #pragma unroll
  for (int nt = 0; nt < 8; ++nt) {
    int col = nt * 16 + l15;
    float g2v = g2[col], b2lv = be2[col];
    #pragma unroll
    for (int j = 0; j < 4; ++j) {
      int g = rowbase + wrow + lg * 4 + j;
      if (g < N)
        h[(size_t)g * 128 + col] = (acc[nt][j] - mean[j]) * rstd[j] * g2v + b2lv;
    }
  }
}

// ---------------- launcher ----------------

extern "C" void kernel_launch(void* const* d_in, const int* in_sizes, int n_in,
                              void* d_out, int out_size, void* d_ws, size_t ws_size,
                              hipStream_t stream) {
  const float* x   = (const float*)d_in[0];
  const int*   ei  = (const int*)d_in[1];
  const float* Win = (const float*)d_in[2];
  const float* b_in= (const float*)d_in[3];
  const float* Wv  = (const float*)d_in[4];
  const float* bv  = (const float*)d_in[5];
  const float* Wo  = (const float*)d_in[6];
  const float* bo  = (const float*)d_in[7];
  const float* W1  = (const float*)d_in[8];
  const float* b1  = (const float*)d_in[9];
  const float* W2  = (const float*)d_in[10];
  const float* b2  = (const float*)d_in[11];
  const float* ln1g= (const float*)d_in[12];
  const float* ln1b= (const float*)d_in[13];
  const float* ln2g= (const float*)d_in[14];
  const float* ln2b= (const float*)d_in[15];
  const float* Wd  = (const float*)d_in[16];
  const float* bd  = (const float*)d_in[17];
  const float* Wg  = (const float*)d_in[18];
  const float* bg  = (const float*)d_in[19];
  const float* Wf  = (const float*)d_in[20];
  const float* bfp = (const float*)d_in[21];

  const int N = in_sizes[0] / 3;
  const int E = in_sizes[1] / 2;

  char* ws = (char*)d_ws;
  float* h = (float*)ws;                     size_t off = (size_t)N * 128 * 4;
  ushort* Wvb = (ushort*)(ws + off);         off += (size_t)3 * 16384 * 2;
  ushort* Wob = (ushort*)(ws + off);         off += (size_t)3 * 16384 * 2;
  ushort* W1b = (ushort*)(ws + off);         off += (size_t)3 * 262144 * 2;
  ushort* W2b = (ushort*)(ws + off);         off += (size_t)3 * 262144 * 2;
  float* degf = (float*)(ws + off);          off += (size_t)N * 4;
  float* tarr = (float*)(ws + off);          off += (size_t)N * 4;
  float* uarr = (float*)(ws + off);          off += (size_t)N * 4;

  conv_bf16_kernel<<<(3 * 16384 + 255) / 256, 256, 0, stream>>>(Wv, Wvb, 3 * 16384);
  conv_bf16_kernel<<<(3 * 16384 + 255) / 256, 256, 0, stream>>>(Wo, Wob, 3 * 16384);
  conv_bf16_kernel<<<(3 * 262144 + 255) / 256, 256, 0, stream>>>(W1, W1b, 3 * 262144);
  conv_bf16_kernel<<<(3 * 262144 + 255) / 256, 256, 0, stream>>>(W2, W2b, 3 * 262144);
  zero_kernel<<<(2 * N + 255) / 256, 256, 0, stream>>>(degf, 2 * N);  // degf + tarr (adjacent)

  embed_kernel<<<((size_t)N * 128 + 255) / 256, 256, 0, stream>>>(x, Win, b_in, h, N);
  deg_kernel<<<((E + 3) / 4 + 255) / 256, 256, 0, stream>>>(ei, degf, E);

  const int grid = (N + 127) / 128;
  for (int l = 0; l < 3; ++l) {
    layer_kernel<<<grid, 512, 0, stream>>>(
        h,
        Wvb + (size_t)l * 16384, Wob + (size_t)l * 16384,
        W1b + (size_t)l * 262144, W2b + (size_t)l * 262144,
        bv + l * 128, bo + l * 128, b1 + l * 2048, b2 + l * 128,
        ln1g + l * 128, ln1b + l * 128, ln2g + l * 128, ln2b + l * 128,
        N);
  }

  z_kernel<<<(N + 3) / 4, 256, 0, stream>>>(h, Wd, bd, degf, uarr, N);
  scatter_kernel<<<((E + 3) / 4 + 255) / 256, 256, 0, stream>>>(ei, uarr, tarr, E);
  out_kernel<<<(N + 255) / 256, 256, 0, stream>>>(degf, uarr, tarr, Wg, bg, Wf, bfp,
                                                  (float*)d_out, N);
}

// Round 4
// 2145.297 us; speedup vs baseline: 1.2915x; 1.1061x over previous
//
#include <hip/hip_runtime.h>
#include <hip/hip_bf16.h>
#include <stdint.h>

typedef __attribute__((ext_vector_type(8))) short short8;
typedef __attribute__((ext_vector_type(4))) float f32x4;

#define LN_EPS 1e-5f

__device__ __forceinline__ ushort f2bf(float f) {
  union { float f; uint32_t u; } v; v.f = f;
  uint32_t u = v.u;
  return (ushort)((u + 0x7FFFu + ((u >> 16) & 1u)) >> 16);
}
__device__ __forceinline__ float bf2f(ushort b) {
  union { uint32_t u; float f; } v; v.u = ((uint32_t)b) << 16;
  return v.f;
}
__device__ __forceinline__ uint32_t cvtpk(float lo, float hi) {
  uint32_t r;
  asm volatile("v_cvt_pk_bf16_f32 %0, %1, %2" : "=v"(r) : "v"(lo), "v"(hi));
  return r;
}

// ---------------- small kernels ----------------

__global__ void conv_bf16_kernel(const float* __restrict__ src, ushort* __restrict__ dst, int n) {
  int i = blockIdx.x * 256 + threadIdx.x;
  if (i < n) dst[i] = f2bf(src[i]);
}

__global__ void zero_kernel(float* __restrict__ p, int n) {
  int i = blockIdx.x * 256 + threadIdx.x;
  if (i < n) p[i] = 0.f;
}

__global__ void embed_kernel(const float* __restrict__ x, const float* __restrict__ Win,
                             const float* __restrict__ b_in, float* __restrict__ h, int N) {
  int i = blockIdx.x * 256 + threadIdx.x;
  if (i >= N * 128) return;
  int n = i >> 7, d = i & 127;
  float v = Win[d*3+0]*x[n*3+0] + Win[d*3+1]*x[n*3+1] + Win[d*3+2]*x[n*3+2] + b_in[d];
  h[i] = fmaxf(v, 0.f);
}

__global__ void deg_kernel(const int* __restrict__ ei, float* __restrict__ degf, int E) {
  int i = blockIdx.x * 256 + threadIdx.x;
  int e0 = i * 4;
  if (e0 + 3 < E) {
    int4 c = *(const int4*)(ei + E + e0);
    atomicAdd(&degf[c.x], 1.0f); atomicAdd(&degf[c.y], 1.0f);
    atomicAdd(&degf[c.z], 1.0f); atomicAdd(&degf[c.w], 1.0f);
  } else {
    for (int e = e0; e < E; ++e) atomicAdd(&degf[ei[E + e]], 1.0f);
  }
}

__global__ void z_kernel(const float* __restrict__ h, const float* __restrict__ wd,
                         const float* __restrict__ bd, const float* __restrict__ degf,
                         float* __restrict__ u, int N) {
  int row = blockIdx.x * 4 + (threadIdx.x >> 6);
  int lane = threadIdx.x & 63;
  if (row >= N) return;
  const float* hr = h + (size_t)row * 128;
  float s = hr[lane] * wd[lane] + hr[64 + lane] * wd[64 + lane];
  #pragma unroll
  for (int o = 32; o >= 1; o >>= 1) s += __shfl_xor(s, o, 64);
  if (lane == 0) {
    float z = fmaxf(s + bd[0], 0.f);
    u[row] = z * rsqrtf(degf[row] + 1.0f);
  }
}

__global__ void scatter_kernel(const int* __restrict__ ei, const float* __restrict__ u,
                               float* __restrict__ t, int E) {
  int i = blockIdx.x * 256 + threadIdx.x;
  int e0 = i * 4;
  if (e0 + 3 < E) {
    int4 r = *(const int4*)(ei + e0);
    int4 c = *(const int4*)(ei + E + e0);
    atomicAdd(&t[c.x], u[r.x]); atomicAdd(&t[c.y], u[r.y]);
    atomicAdd(&t[c.z], u[r.z]); atomicAdd(&t[c.w], u[r.w]);
  } else {
    for (int e = e0; e < E; ++e) atomicAdd(&t[ei[E + e]], u[ei[e]]);
  }
}

__global__ void out_kernel(const float* __restrict__ degf, const float* __restrict__ u,
                           const float* __restrict__ t, const float* __restrict__ wg,
                           const float* __restrict__ bg, const float* __restrict__ wf,
                           const float* __restrict__ bfp, float* __restrict__ out, int N) {
  int n = blockIdx.x * 256 + threadIdx.x;
  if (n >= N) return;
  float dis = rsqrtf(degf[n] + 1.0f);
  float tf = dis * (t[n] + u[n]);
  float acc = bfp[0];
  #pragma unroll
  for (int j = 0; j < 32; ++j) acc += wf[j] * fmaxf(tf * wg[j] + bg[j], 0.f);
  out[n] = acc;
}

// ---------------- fused transformer layer ----------------
// 256-row tile, 8 waves x 32 rows. LDS: hA[256][128]bf16 64KB (swz, all accesses
// wave-private rows -> NO hA barriers) + wbuf 2x32KB double-buffered = 128KB.
// FF intermediate u stays in REGISTERS: uT = mfma(W1c, h1) gives r=lane&15 (lane-
// local); repack to W2 A-frags via cvt_pk_bf16 + shfl. One barrier per FF chunk.
// MFMA 16x16x32 bf16 (empirically verified): A: row=l&15,k=8*(l>>4)+j;
// B: col=l&15,same k; C/D: col=l&15,row=4*(l>>4)+reg.

#define MFMA16(a, b, c) __builtin_amdgcn_mfma_f32_16x16x32_bf16(a, b, c, 0, 0, 0)

__global__ __launch_bounds__(512, 2) void layer_kernel(
    float* __restrict__ h,
    const ushort* __restrict__ Wv, const ushort* __restrict__ Wo,
    const ushort* __restrict__ W1, const ushort* __restrict__ W2,
    const float* __restrict__ bv, const float* __restrict__ bo,
    const float* __restrict__ b1, const float* __restrict__ b2,
    const float* __restrict__ g1, const float* __restrict__ be1,
    const float* __restrict__ g2, const float* __restrict__ be2,
    int N)
{
  __shared__ ushort hA[256 * 128];     // row stride 256B, swz byte ^= (row&7)<<4
  __shared__ ushort wbuf[2 * 16384];   // half: W1c/Wv [.][128] @0 + W2c [128][64] @16KB

  const int tid = threadIdx.x;
  const int lane = tid & 63;
  const int wave = tid >> 6;
  const int l15 = lane & 15;
  const int lg = lane >> 4;
  const int rowbase = blockIdx.x * 256;
  const int wrow = wave * 32;
  const int ssw = (l15 & 7) << 4;

  // ---- stage h (fp32 -> bf16 LDS) + Wv (half0) + Wo (half1) ----
  #pragma unroll
  for (int i = 0; i < 8; ++i) {
    int u = tid + i * 512;            // short8 units of hA (4096)
    int row = u >> 4, k8 = u & 15;
    int g = rowbase + row;
    float4 f0 = make_float4(0.f,0.f,0.f,0.f), f1 = f0;
    if (g < N) {
      const float4* p = (const float4*)(h + (size_t)g * 128 + k8 * 8);
      f0 = p[0]; f1 = p[1];
    }
    short8 v;
    v[0]=(short)f2bf(f0.x); v[1]=(short)f2bf(f0.y); v[2]=(short)f2bf(f0.z); v[3]=(short)f2bf(f0.w);
    v[4]=(short)f2bf(f1.x); v[5]=(short)f2bf(f1.y); v[6]=(short)f2bf(f1.z); v[7]=(short)f2bf(f1.w);
    *(short8*)((char*)hA + ((row << 8) + ((k8 << 4) ^ ((row & 7) << 4)))) = v;
  }
  #pragma unroll
  for (int i = 0; i < 4; ++i) {
    int u = tid + i * 512;            // 2048 units each
    int row = u >> 4, k8 = u & 15;
    int off = (row << 8) + ((k8 << 4) ^ ((row & 7) << 4));
    *(short8*)((char*)wbuf + off)         = *(const short8*)(Wv + u * 8);
    *(short8*)((char*)wbuf + 32768 + off) = *(const short8*)(Wo + u * 8);
  }
  __syncthreads();

  // prefetch FF chunk0 into regs (hidden under GEMM1/2)
  short8 wr[4];
  #pragma unroll
  for (int i = 0; i < 4; ++i) {
    int c = tid + i * 512;
    wr[i] = (c < 1024) ? *(const short8*)(W1 + c * 8)
                       : *(const short8*)(W2 + (size_t)((c - 1024) >> 3) * 2048 + ((c - 1024) & 7) * 8);
  }

  // ---- GEMM1: t = h @ Wv^T  (wave: 32 rows x 128 cols) ----
  f32x4 tC[2][8];
  #pragma unroll
  for (int rt = 0; rt < 2; ++rt)
    #pragma unroll
    for (int ct = 0; ct < 8; ++ct) tC[rt][ct] = (f32x4){0.f,0.f,0.f,0.f};
  __builtin_amdgcn_s_setprio(1);
  #pragma unroll
  for (int ks = 0; ks < 4; ++ks) {
    int asw = (ks * 64 + lg * 16) ^ ssw;
    short8 a0 = *(const short8*)((char*)hA + (((wrow + l15) << 8) + asw));
    short8 a1 = *(const short8*)((char*)hA + (((wrow + 16 + l15) << 8) + asw));
    #pragma unroll
    for (int ct = 0; ct < 8; ++ct) {
      short8 b = *(const short8*)((char*)wbuf + (((ct * 16 + l15) << 8) + asw));
      tC[0][ct] = MFMA16(a0, b, tC[0][ct]);
      tC[1][ct] = MFMA16(a1, b, tC[1][ct]);
    }
  }
  __builtin_amdgcn_s_setprio(0);
  // t + bv -> hA (own rows; overwrites h rows of this wave only)
  #pragma unroll
  for (int ct = 0; ct < 8; ++ct) {
    int col = ct * 16 + l15;
    float bvv = bv[col];
    #pragma unroll
    for (int rt = 0; rt < 2; ++rt)
      #pragma unroll
      for (int j = 0; j < 4; ++j) {
        int lr = wrow + rt * 16 + lg * 4 + j;
        *(ushort*)((char*)hA + ((lr << 8) + ((col * 2) ^ ((lr & 7) << 4)))) =
            f2bf(tC[rt][ct][j] + bvv);
      }
  }
  __syncthreads();   // all GEMM1 Wv reads done (half0 gets chunk0 later)

  // ---- GEMM2: attn = t @ Wo^T ----
  #pragma unroll
  for (int rt = 0; rt < 2; ++rt)
    #pragma unroll
    for (int ct = 0; ct < 8; ++ct) tC[rt][ct] = (f32x4){0.f,0.f,0.f,0.f};
  __builtin_amdgcn_s_setprio(1);
  #pragma unroll
  for (int ks = 0; ks < 4; ++ks) {
    int asw = (ks * 64 + lg * 16) ^ ssw;
    short8 a0 = *(const short8*)((char*)hA + (((wrow + l15) << 8) + asw));
    short8 a1 = *(const short8*)((char*)hA + (((wrow + 16 + l15) << 8) + asw));
    #pragma unroll
    for (int ct = 0; ct < 8; ++ct) {
      short8 b = *(const short8*)((char*)wbuf + 32768 + (((ct * 16 + l15) << 8) + asw));
      tC[0][ct] = MFMA16(a0, b, tC[0][ct]);
      tC[1][ct] = MFMA16(a1, b, tC[1][ct]);
    }
  }
  __builtin_amdgcn_s_setprio(0);

  // ---- residual1 (fp32 re-read of h) + bo, LN1 -> h1 (bf16) into hA ----
  float sum[2][4] = {{0,0,0,0},{0,0,0,0}};
  float sq[2][4]  = {{0,0,0,0},{0,0,0,0}};
  #pragma unroll
  for (int rt = 0; rt < 2; ++rt)
    #pragma unroll
    for (int ct = 0; ct < 8; ++ct) {
      float bov = bo[ct * 16 + l15];
      #pragma unroll
      for (int j = 0; j < 4; ++j) {
        int g = rowbase + wrow + rt * 16 + lg * 4 + j;
        float hv = (g < N) ? h[(size_t)g * 128 + ct * 16 + l15] : 0.f;
        float v = tC[rt][ct][j] + bov + hv;
        tC[rt][ct][j] = v;
        sum[rt][j] += v; sq[rt][j] += v * v;
      }
    }
  #pragma unroll
  for (int o = 1; o < 16; o <<= 1)
    #pragma unroll
    for (int rt = 0; rt < 2; ++rt)
      #pragma unroll
      for (int j = 0; j < 4; ++j) {
        sum[rt][j] += __shfl_xor(sum[rt][j], o, 64);
        sq[rt][j]  += __shfl_xor(sq[rt][j],  o, 64);
      }
  float mean[2][4], rstd[2][4];
  #pragma unroll
  for (int rt = 0; rt < 2; ++rt)
    #pragma unroll
    for (int j = 0; j < 4; ++j) {
      mean[rt][j] = sum[rt][j] * (1.f / 128.f);
      float var = sq[rt][j] * (1.f / 128.f) - mean[rt][j] * mean[rt][j];
      rstd[rt][j] = rsqrtf(var + LN_EPS);
    }
  #pragma unroll
  for (int ct = 0; ct < 8; ++ct) {
    int col = ct * 16 + l15;
    float g1v = g1[col], b1v = be1[col];
    #pragma unroll
    for (int rt = 0; rt < 2; ++rt)
      #pragma unroll
      for (int j = 0; j < 4; ++j) {
        int lr = wrow + rt * 16 + lg * 4 + j;
        float hh = (tC[rt][ct][j] - mean[rt][j]) * rstd[rt][j] * g1v + b1v;
        *(ushort*)((char*)hA + ((lr << 8) + ((col * 2) ^ ((lr & 7) << 4)))) = f2bf(hh);
      }
  }

  // write chunk0 -> half0, prefetch chunk1
  #pragma unroll
  for (int i = 0; i < 4; ++i) {
    int c = tid + i * 512;
    if (c < 1024) {
      int row = c >> 4, k8 = c & 15;
      *(short8*)((char*)wbuf + ((row << 8) + ((k8 << 4) ^ ((row & 7) << 4)))) = wr[i];
    } else {
      int cc = c - 1024;
      int row = cc >> 3, k8 = cc & 7;
      *(short8*)((char*)wbuf + 16384 + ((row << 7) + ((k8 << 4) ^ ((row & 7) << 4)))) = wr[i];
    }
  }
  {
    const ushort* W1c = W1 + 64 * 128;
    const ushort* W2c = W2 + 64;
    #pragma unroll
    for (int i = 0; i < 4; ++i) {
      int c = tid + i * 512;
      wr[i] = (c < 1024) ? *(const short8*)(W1c + c * 8)
                         : *(const short8*)(W2c + (size_t)((c - 1024) >> 3) * 2048 + ((c - 1024) & 7) * 8);
    }
  }
  __syncthreads();   // chunk0 ready (also: all Wo reads done before chunk1 write)

  // ---- FF: acc = relu(h1@W1c^T + b1c) @ W2c^T, 32 chunks of F=64, u in regs ----
  f32x4 acc[2][8];
  #pragma unroll
  for (int rt = 0; rt < 2; ++rt)
    #pragma unroll
    for (int ct = 0; ct < 8; ++ct) acc[rt][ct] = (f32x4){0.f,0.f,0.f,0.f};

  for (int ch = 0; ch < 32; ++ch) {
    const int base = (ch & 1) << 15;
    // uT[ft][rt] = W1c @ h1^T : D row = f_local = 4*lg+j, col = r_local = l15
    f32x4 uT[4][2];
    #pragma unroll
    for (int ft = 0; ft < 4; ++ft)
      #pragma unroll
      for (int rt = 0; rt < 2; ++rt) uT[ft][rt] = (f32x4){0.f,0.f,0.f,0.f};
    __builtin_amdgcn_s_setprio(1);
    #pragma unroll
    for (int ks = 0; ks < 4; ++ks) {
      int asw = (ks * 64 + lg * 16) ^ ssw;
      short8 bh[2];
      #pragma unroll
      for (int rt = 0; rt < 2; ++rt)
        bh[rt] = *(const short8*)((char*)hA + (((wrow + rt * 16 + l15) << 8) + asw));
      #pragma unroll
      for (int ft = 0; ft < 4; ++ft) {
        short8 aw = *(const short8*)((char*)wbuf + base + (((ft * 16 + l15) << 8) + asw));
        uT[ft][0] = MFMA16(aw, bh[0], uT[ft][0]);
        uT[ft][1] = MFMA16(aw, bh[1], uT[ft][1]);
      }
    }
    __builtin_amdgcn_s_setprio(0);
    // bias + relu (f = ch*64 + ft*16 + 4*lg + j)
    #pragma unroll
    for (int ft = 0; ft < 4; ++ft) {
      float4 b4 = *(const float4*)(b1 + ch * 64 + ft * 16 + lg * 4);
      #pragma unroll
      for (int rt = 0; rt < 2; ++rt)
        #pragma unroll
        for (int j = 0; j < 4; ++j)
          uT[ft][rt][j] = fmaxf(uT[ft][rt][j] + ((const float*)&b4)[j], 0.f);
    }
    // repack uT -> W2 A-frags: lane needs u[r=l15, f=32*ks2+8*lg+{0..7}]
    short8 fr[2][2];
    {
      const int s0 = l15 + ((lg & 1) << 5);
      const int s1 = s0 + 16;
      const bool hiq = (lg >= 2);
      #pragma unroll
      for (int ks2 = 0; ks2 < 2; ++ks2)
        #pragma unroll
        for (int rt = 0; rt < 2; ++rt) {
          uint32_t pA0 = cvtpk(uT[2*ks2][rt][0],   uT[2*ks2][rt][1]);
          uint32_t pA1 = cvtpk(uT[2*ks2][rt][2],   uT[2*ks2][rt][3]);
          uint32_t pB0 = cvtpk(uT[2*ks2+1][rt][0], uT[2*ks2+1][rt][1]);
          uint32_t pB1 = cvtpk(uT[2*ks2+1][rt][2], uT[2*ks2+1][rt][3]);
          uint32_t d0 = __shfl((int)pA0, s0, 64), d1 = __shfl((int)pA1, s0, 64);
          uint32_t d2 = __shfl((int)pA0, s1, 64), d3 = __shfl((int)pA1, s1, 64);
          uint32_t e0 = __shfl((int)pB0, s0, 64), e1 = __shfl((int)pB1, s0, 64);
          uint32_t e2 = __shfl((int)pB0, s1, 64), e3 = __shfl((int)pB1, s1, 64);
          union { uint32_t u[4]; short8 s; } f;
          f.u[0] = hiq ? e0 : d0; f.u[1] = hiq ? e1 : d1;
          f.u[2] = hiq ? e2 : d2; f.u[3] = hiq ? e3 : d3;
          fr[rt][ks2] = f.s;
        }
    }
    // acc += u @ W2c^T
    __builtin_amdgcn_s_setprio(1);
    #pragma unroll
    for (int ks2 = 0; ks2 < 2; ++ks2) {
      int asw2 = (ks2 * 64 + lg * 16) ^ ssw;
      #pragma unroll
      for (int ct = 0; ct < 8; ++ct) {
        short8 b = *(const short8*)((char*)wbuf + base + 16384 + (((ct * 16 + l15) << 7) + asw2));
        acc[0][ct] = MFMA16(fr[0][ks2], b, acc[0][ct]);
        acc[1][ct] = MFMA16(fr[1][ks2], b, acc[1][ct]);
      }
    }
    __builtin_amdgcn_s_setprio(0);

    if (ch < 31) {
      const int nbase = ((ch + 1) & 1) << 15;
      #pragma unroll
      for (int i = 0; i < 4; ++i) {
        int c = tid + i * 512;
        if (c < 1024) {
          int row = c >> 4, k8 = c & 15;
          *(short8*)((char*)wbuf + nbase + ((row << 8) + ((k8 << 4) ^ ((row & 7) << 4)))) = wr[i];
        } else {
          int cc = c - 1024;
          int row = cc >> 3, k8 = cc & 7;
          *(short8*)((char*)wbuf + nbase + 16384 + ((row << 7) + ((k8 << 4) ^ ((row & 7) << 4)))) = wr[i];
        }
      }
      if (ch < 30) {
        const ushort* W1c = W1 + (size_t)(ch + 2) * 64 * 128;
        const ushort* W2c = W2 + (ch + 2) * 64;
        #pragma unroll
        for (int i = 0; i < 4; ++i) {
          int c = tid + i * 512;
          wr[i] = (c < 1024) ? *(const short8*)(W1c + c * 8)
                             : *(const short8*)(W2c + (size_t)((c - 1024) >> 3) * 2048 + ((c - 1024) & 7) * 8);
        }
      }
      __syncthreads();
    }
  }

  // ---- residual2 (h1 from hA bf16) + b2, LN2 -> h (fp32 global) ----
  #pragma unroll
  for (int rt = 0; rt < 2; ++rt)
    #pragma unroll
    for (int j = 0; j < 4; ++j) { sum[rt][j] = 0.f; sq[rt][j] = 0.f; }
  #pragma unroll
  for (int rt = 0; rt < 2; ++rt)
    #pragma unroll
    for (int ct = 0; ct < 8; ++ct) {
      int col = ct * 16 + l15;
      float b2v = b2[col];
      #pragma unroll
      for (int j = 0; j < 4; ++j) {
        int lr = wrow + rt * 16 + lg * 4 + j;
        float h1v = bf2f(*(const ushort*)((char*)hA + ((lr << 8) + ((col * 2) ^ ((lr & 7) << 4)))));
        float v = acc[rt][ct][j] + b2v + h1v;
        acc[rt][ct][j] = v;
        sum[rt][j] += v; sq[rt][j] += v * v;
      }
    }
  #pragma unroll
  for (int o = 1; o < 16; o <<= 1)
    #pragma unroll
    for (int rt = 0; rt < 2; ++rt)
      #pragma unroll
      for (int j = 0; j < 4; ++j) {
        sum[rt][j] += __shfl_xor(sum[rt][j], o, 64);
        sq[rt][j]  += __shfl_xor(sq[rt][j],  o, 64);
      }
  #pragma unroll
  for (int rt = 0; rt < 2; ++rt)
    #pragma unroll
    for (int j = 0; j < 4; ++j) {
      mean[rt][j] = sum[rt][j] * (1.f / 128.f);
      float var = sq[rt][j] * (1.f / 128.f) - mean[rt][j] * mean[rt][j];
      rstd[rt][j] = rsqrtf(var + LN_EPS);
    }
  #pragma unroll
  for (int rt = 0; rt < 2; ++rt)
    #pragma unroll
    for (int ct = 0; ct < 8; ++ct) {
      int col = ct * 16 + l15;
      float g2v = g2[col], b2lv = be2[col];
      #pragma unroll
      for (int j = 0; j < 4; ++j) {
        int g = rowbase + wrow + rt * 16 + lg * 4 + j;
        if (g < N)
          h[(size_t)g * 128 + col] = (acc[rt][ct][j] - mean[rt][j]) * rstd[rt][j] * g2v + b2lv;
      }
    }
}

// ---------------- launcher ----------------

extern "C" void kernel_launch(void* const* d_in, const int* in_sizes, int n_in,
                              void* d_out, int out_size, void* d_ws, size_t ws_size,
                              hipStream_t stream) {
  const float* x   = (const float*)d_in[0];
  const int*   ei  = (const int*)d_in[1];
  const float* Win = (const float*)d_in[2];
  const float* b_in= (const float*)d_in[3];
  const float* Wv  = (const float*)d_in[4];
  const float* bv  = (const float*)d_in[5];
  const float* Wo  = (const float*)d_in[6];
  const float* bo  = (const float*)d_in[7];
  const float* W1  = (const float*)d_in[8];
  const float* b1  = (const float*)d_in[9];
  const float* W2  = (const float*)d_in[10];
  const float* b2  = (const float*)d_in[11];
  const float* ln1g= (const float*)d_in[12];
  const float* ln1b= (const float*)d_in[13];
  const float* ln2g= (const float*)d_in[14];
  const float* ln2b= (const float*)d_in[15];
  const float* Wd  = (const float*)d_in[16];
  const float* bd  = (const float*)d_in[17];
  const float* Wg  = (const float*)d_in[18];
  const float* bg  = (const float*)d_in[19];
  const float* Wf  = (const float*)d_in[20];
  const float* bfp = (const float*)d_in[21];

  const int N = in_sizes[0] / 3;
  const int E = in_sizes[1] / 2;

  char* ws = (char*)d_ws;
  float* h = (float*)ws;                     size_t off = (size_t)N * 128 * 4;
  ushort* Wvb = (ushort*)(ws + off);         off += (size_t)3 * 16384 * 2;
  ushort* Wob = (ushort*)(ws + off);         off += (size_t)3 * 16384 * 2;
  ushort* W1b = (ushort*)(ws + off);         off += (size_t)3 * 262144 * 2;
  ushort* W2b = (ushort*)(ws + off);         off += (size_t)3 * 262144 * 2;
  float* degf = (float*)(ws + off);          off += (size_t)N * 4;
  float* tarr = (float*)(ws + off);          off += (size_t)N * 4;
  float* uarr = (float*)(ws + off);          off += (size_t)N * 4;

  conv_bf16_kernel<<<(3 * 16384 + 255) / 256, 256, 0, stream>>>(Wv, Wvb, 3 * 16384);
  conv_bf16_kernel<<<(3 * 16384 + 255) / 256, 256, 0, stream>>>(Wo, Wob, 3 * 16384);
  conv_bf16_kernel<<<(3 * 262144 + 255) / 256, 256, 0, stream>>>(W1, W1b, 3 * 262144);
  conv_bf16_kernel<<<(3 * 262144 + 255) / 256, 256, 0, stream>>>(W2, W2b, 3 * 262144);
  zero_kernel<<<(2 * N + 255) / 256, 256, 0, stream>>>(degf, 2 * N);  // degf + tarr adjacent

  embed_kernel<<<((size_t)N * 128 + 255) / 256, 256, 0, stream>>>(x, Win, b_in, h, N);
  deg_kernel<<<((E + 3) / 4 + 255) / 256, 256, 0, stream>>>(ei, degf, E);

  const int grid = (N + 255) / 256;
  for (int l = 0; l < 3; ++l) {
    layer_kernel<<<grid, 512, 0, stream>>>(
        h,
        Wvb + (size_t)l * 16384, Wob + (size_t)l * 16384,
        W1b + (size_t)l * 262144, W2b + (size_t)l * 262144,
        bv + l * 128, bo + l * 128, b1 + l * 2048, b2 + l * 128,
        ln1g + l * 128, ln1b + l * 128, ln2g + l * 128, ln2b + l * 128,
        N);
  }

  z_kernel<<<(N + 3) / 4, 256, 0, stream>>>(h, Wd, bd, degf, uarr, N);
  scatter_kernel<<<((E + 3) / 4 + 255) / 256, 256, 0, stream>>>(ei, uarr, tarr, E);
  out_kernel<<<(N + 255) / 256, 256, 0, stream>>>(degf, uarr, tarr, Wg, bg, Wf, bfp,
                                                  (float*)d_out, N);
}